// Round 4
// baseline (241.570 us; speedup 1.0000x reference)
//
#include <hip/hip_runtime.h>
#include <hip/hip_cooperative_groups.h>
#include <math.h>

namespace cg = cooperative_groups;

#define N_NODES 50000
#define N_EDGES 800000
#define HIDDEN  256
#define OUT_DIM 10
#define LN_EPS  1e-5f

#define NP    8                    // node partitions
#define PART  (N_NODES / NP)       // 6250 nodes per partition
#define ES    32                   // edge slices
#define EPSE  (N_EDGES / ES)       // 25000 edges per slice
#define NBLK  (NP * ES)            // 256 blocks == 256 CUs (co-resident)
#define NTHR  1024
#define NWAVE (NBLK * NTHR / 64)   // 4096 waves

// Single cooperative kernel: all phases fused, grid.sync() between them.
// No global atomics anywhere; all cross-block combining via partial buffers
// + deterministic reduction.
__global__ __launch_bounds__(NTHR) void mega_kernel(
    const int* __restrict__ src, const int* __restrict__ dst,
    const float2* __restrict__ nf,
    const float* __restrict__ Wg, const float* __restrict__ bg,
    const float* __restrict__ gamma, const float* __restrict__ beta,
    const float* __restrict__ Wh, const float* __restrict__ bh,
    const float* __restrict__ Wo, const float* __restrict__ bo,
    unsigned* __restrict__ degp,   // [ES][N] degree partials
    float* __restrict__ Tpart,     // [ES][2N] scatter partials
    float* __restrict__ dinv,      // [N]
    float2* __restrict__ y,        // [N]  y = dinv * x
    float* __restrict__ T,         // [2N] reduced scatter
    float* __restrict__ Ppart,     // [NBLK][HIDDEN] pooled partials
    float* __restrict__ out)
{
    cg::grid_group grid = cg::this_grid();
    __shared__ float smem[2 * PART];           // 50 KB, reused per phase

    const int tid   = threadIdx.x;
    const int bid   = blockIdx.x;
    const int slice = bid & (ES - 1);
    const int part  = bid >> 5;                // bid / ES
    const int base  = part * PART;
    const int e0    = slice * EPSE;

    // ---------------- phase 1: privatized degree histogram ----------------
    {
        unsigned* hist = (unsigned*)smem;
        for (int i = tid; i < PART; i += NTHR) hist[i] = 0u;
        __syncthreads();
        for (int e = e0 + tid; e < e0 + EPSE; e += NTHR) {
            const unsigned r = (unsigned)(dst[e] - base);
            if (r < PART) atomicAdd(&hist[r], 1u);
        }
        __syncthreads();
        unsigned* outp = degp + (size_t)slice * N_NODES + base;
        for (int i = tid; i < PART; i += NTHR) outp[i] = hist[i];
    }
    grid.sync();

    // ---------------- phase 2: deg -> dinv, y = dinv * x ------------------
    {
        const int gt = bid * NTHR + tid;
        if (gt < N_NODES) {
            unsigned d = 0;
            #pragma unroll
            for (int s = 0; s < ES; ++s) d += degp[(size_t)s * N_NODES + gt];
            const float di = rsqrtf((float)d + 1.0f);
            dinv[gt] = di;
            const float2 x = nf[gt];
            y[gt] = make_float2(di * x.x, di * x.y);
        }
    }
    grid.sync();

    // ---------------- phase 3: privatized edge scatter --------------------
    // T[d] += y[src]  (dinv[d] factor applied in phase 4b)
    {
        float* Tl = smem;
        for (int i = tid; i < 2 * PART; i += NTHR) Tl[i] = 0.f;
        __syncthreads();
        for (int e = e0 + tid; e < e0 + EPSE; e += NTHR) {
            const unsigned r = (unsigned)(dst[e] - base);
            if (r < PART) {
                const float2 ys = y[src[e]];
                atomicAdd(&Tl[2 * r],     ys.x);
                atomicAdd(&Tl[2 * r + 1], ys.y);
            }
        }
        __syncthreads();
        float* outp = Tpart + (size_t)slice * (2 * N_NODES) + 2 * base;
        for (int i = tid; i < 2 * PART; i += NTHR) outp[i] = Tl[i];
    }
    grid.sync();

    // ---------------- phase 4a: coalesced Tpart -> T reduce ---------------
    {
        const int gt = bid * NTHR + tid;
        for (int i = gt; i < 2 * N_NODES; i += NBLK * NTHR) {
            float s = 0.f;
            #pragma unroll
            for (int p = 0; p < ES; ++p) s += Tpart[(size_t)p * (2 * N_NODES) + i];
            T[i] = s;
        }
    }
    grid.sync();

    // -------- phase 4b: GCN expand + ReLU + LayerNorm + pool partials -----
    // wave-per-node; s[n] = dinv[n]*(T[n] + y[n]); lane owns 4 columns
    {
        const int lane = tid & 63;
        const int wv   = tid >> 6;
        const int gw   = (bid * NTHR + tid) >> 6;

        const float4 w0  = *reinterpret_cast<const float4*>(&Wg[lane * 4]);
        const float4 w1  = *reinterpret_cast<const float4*>(&Wg[HIDDEN + lane * 4]);
        const float4 bgv = *reinterpret_cast<const float4*>(&bg[lane * 4]);
        const float4 gv  = *reinterpret_cast<const float4*>(&gamma[lane * 4]);
        const float4 bv  = *reinterpret_cast<const float4*>(&beta[lane * 4]);

        float a0 = 0.f, a1 = 0.f, a2 = 0.f, a3 = 0.f;

        for (int n = gw; n < N_NODES; n += NWAVE) {
            const float di = dinv[n];
            const float2 tn = *reinterpret_cast<const float2*>(&T[2 * n]);
            const float2 yn = y[n];
            const float s0 = di * (tn.x + yn.x);
            const float s1 = di * (tn.y + yn.y);

            float v0 = fmaxf(fmaf(s1, w1.x, fmaf(s0, w0.x, bgv.x)), 0.f);
            float v1 = fmaxf(fmaf(s1, w1.y, fmaf(s0, w0.y, bgv.y)), 0.f);
            float v2 = fmaxf(fmaf(s1, w1.z, fmaf(s0, w0.z, bgv.z)), 0.f);
            float v3 = fmaxf(fmaf(s1, w1.w, fmaf(s0, w0.w, bgv.w)), 0.f);

            float sum = v0 + v1 + v2 + v3;
            float sq  = v0 * v0 + v1 * v1 + v2 * v2 + v3 * v3;
            #pragma unroll
            for (int o = 1; o < 64; o <<= 1) {
                sum += __shfl_xor(sum, o, 64);
                sq  += __shfl_xor(sq,  o, 64);
            }
            const float mu   = sum * (1.0f / HIDDEN);
            const float var  = sq * (1.0f / HIDDEN) - mu * mu;
            const float rstd = rsqrtf(var + LN_EPS);

            a0 += (v0 - mu) * rstd * gv.x + bv.x;
            a1 += (v1 - mu) * rstd * gv.y + bv.y;
            a2 += (v2 - mu) * rstd * gv.z + bv.z;
            a3 += (v3 - mu) * rstd * gv.w + bv.w;
        }

        // block-level reduce of 16 waves -> one partial row per block
        float* red = smem;                     // [16][HIDDEN] floats
        red[wv * HIDDEN + lane * 4 + 0] = a0;
        red[wv * HIDDEN + lane * 4 + 1] = a1;
        red[wv * HIDDEN + lane * 4 + 2] = a2;
        red[wv * HIDDEN + lane * 4 + 3] = a3;
        __syncthreads();
        if (tid < HIDDEN) {
            float s = 0.f;
            #pragma unroll
            for (int w = 0; w < 16; ++w) s += red[w * HIDDEN + tid];
            Ppart[(size_t)bid * HIDDEN + tid] = s;
        }
    }
    grid.sync();

    // ---------------- phase 5: pooled reduce + MLP head (block 0) ---------
    if (bid == 0) {
        float* red4 = smem;                    // [4][HIDDEN]
        float* p    = smem + 4 * HIDDEN;       // [HIDDEN]
        float* z    = p + HIDDEN;              // [HIDDEN]
        float* lg   = z + HIDDEN;              // [OUT_DIM]

        const int j = tid & (HIDDEN - 1);
        const int g = tid >> 8;                // 0..3
        float s = 0.f;
        for (int b = g * 64; b < g * 64 + 64; ++b)
            s += Ppart[(size_t)b * HIDDEN + j];
        red4[g * HIDDEN + j] = s;
        __syncthreads();

        if (tid < HIDDEN)
            p[tid] = red4[tid] + red4[HIDDEN + tid] + red4[2 * HIDDEN + tid] + red4[3 * HIDDEN + tid];
        __syncthreads();

        if (tid < HIDDEN) {
            float s2 = bh[tid];
            for (int k = 0; k < HIDDEN; ++k) s2 = fmaf(p[k], Wh[k * HIDDEN + tid], s2);
            z[tid] = fmaxf(s2, 0.f);
        }
        __syncthreads();

        if (tid < OUT_DIM) {
            float t = bo[tid];
            for (int k = 0; k < HIDDEN; ++k) t = fmaf(z[k], Wo[k * OUT_DIM + tid], t);
            lg[tid] = t;
        }
        __syncthreads();

        if (tid == 0) {
            float m = lg[0];
            for (int k = 1; k < OUT_DIM; ++k) m = fmaxf(m, lg[k]);
            float sum = 0.f;
            for (int k = 0; k < OUT_DIM; ++k) sum += expf(lg[k] - m);
            const float lse = m + logf(sum);
            for (int k = 0; k < OUT_DIM; ++k) out[k] = lg[k] - lse;
        }
    }
}

// ---------------------------------------------------------------- launch ----
extern "C" void kernel_launch(void* const* d_in, const int* in_sizes, int n_in,
                              void* d_out, int out_size, void* d_ws, size_t ws_size,
                              hipStream_t stream) {
    const float2* nf   = (const float2*)d_in[0];  // [N, 2]
    const int*   ei    = (const int*)  d_in[1];   // [2, E] int32
    const float* Wg    = (const float*)d_in[2];
    const float* bg    = (const float*)d_in[3];
    const float* gamma = (const float*)d_in[4];
    const float* beta  = (const float*)d_in[5];
    const float* Wh    = (const float*)d_in[6];
    const float* bh    = (const float*)d_in[7];
    const float* Wo    = (const float*)d_in[8];
    const float* bo    = (const float*)d_in[9];
    float* out = (float*)d_out;

    const int* srcp = ei;
    const int* dstp = ei + N_EDGES;

    // workspace: degp [ES*N] u32 | Tpart [ES*2N] | dinv [N] | y [2N] | T [2N]
    //            | Ppart [NBLK*H]   (~20.7 MB total)
    unsigned* degp = (unsigned*)d_ws;
    float* Tpart   = (float*)d_ws + (size_t)ES * N_NODES;
    float* dinvp   = Tpart + (size_t)ES * 2 * N_NODES;
    float* yp      = dinvp + N_NODES;
    float* Tp      = yp + 2 * N_NODES;
    float* Ppart   = Tp + 2 * N_NODES;

    void* args[] = {
        (void*)&srcp, (void*)&dstp, (void*)&nf,
        (void*)&Wg, (void*)&bg, (void*)&gamma, (void*)&beta,
        (void*)&Wh, (void*)&bh, (void*)&Wo, (void*)&bo,
        (void*)&degp, (void*)&Tpart, (void*)&dinvp, (void*)&yp,
        (void*)&Tp, (void*)&Ppart, (void*)&out
    };
    hipLaunchCooperativeKernel((const void*)mega_kernel, dim3(NBLK), dim3(NTHR),
                               args, 0, stream);
}